// Round 2
// baseline (227.236 us; speedup 1.0000x reference)
//
#include <hip/hip_runtime.h>

#define NN 50000
#define NE 800000
#define DD 128

#define CAP 64                                     // slots per node bucket (P(deg>=64) ~ 1e-55)
#define FIX_SCALE 16777216.0f                      // 2^24
#define NWELEM 16384                               // per weight matrix
#define GEMM_GRID ((NN + 127) / 128)               // 391

// two-level bucket sort params
#define SHIFT2 7
#define BWID 128                                   // nodes per coarse bucket (1<<SHIFT2)
#define NBUCK ((NN + BWID - 1) / BWID)             // 391 coarse buckets
#define CAP2 2560                                  // slots per coarse bucket (mean 2048, +11 sigma)
#define NB1 512                                    // scatter/histogram blocks
#define EPB ((NE + NB1 - 1) / NB1)                 // 1563 edges per block
#define NBK_PAD 392                                // hist row stride

typedef __attribute__((ext_vector_type(8))) short short8;
typedef __attribute__((ext_vector_type(4))) float floatx4;
typedef __attribute__((ext_vector_type(4))) _Float16 half4;
typedef __attribute__((ext_vector_type(8))) _Float16 half8;

// ---------------- bf16 split (truncation; err ~2^-16 rel) ----------------

__device__ __forceinline__ void split_trunc(float x, short& hi, short& lo) {
    unsigned uh = __float_as_uint(x) >> 16;
    hi = (short)uh;
    float r = x - __uint_as_float(uh << 16);
    lo = (short)(__float_as_uint(r) >> 16);
}

// ---------------- stage 1: per-block edge histogram (fused with W split) ----------------

__global__ __launch_bounds__(256) void init_hist(const int* __restrict__ col,
                                                 unsigned* __restrict__ hist,
                                                 const float* __restrict__ W1, const float* __restrict__ W2,
                                                 unsigned short* __restrict__ w1hi, unsigned short* __restrict__ w1lo,
                                                 unsigned short* __restrict__ w2hi, unsigned short* __restrict__ w2lo) {
    if (blockIdx.x < NB1) {
        __shared__ unsigned h[NBUCK];
        for (int k = threadIdx.x; k < NBUCK; k += 256) h[k] = 0u;
        __syncthreads();
        int e0 = blockIdx.x * EPB;
        int e1 = min(e0 + EPB, NE);
        for (int e = e0 + (int)threadIdx.x; e < e1; e += 256) {
            atomicAdd(&h[col[e] >> SHIFT2], 1u);
        }
        __syncthreads();
        unsigned* hb = hist + (size_t)blockIdx.x * NBK_PAD;
        for (int k = threadIdx.x; k < NBUCK; k += 256) hb[k] = h[k];
    } else {
        int u = (blockIdx.x - NB1) * 256 + threadIdx.x;     // [0, 2*NWELEM)
        int which = u >> 14;
        int idx = u & (NWELEM - 1);
        int k = idx >> 7, n = idx & 127;
        const float* W = which ? W2 : W1;
        unsigned short* whi = which ? w2hi : w1hi;
        unsigned short* wlo = which ? w2lo : w1lo;
        short h, l;
        split_trunc(W[idx], h, l);
        whi[n * DD + k] = (unsigned short)h;
        wlo[n * DD + k] = (unsigned short)l;
    }
}

// ---------------- stage 2: per-bucket exclusive prefix over blocks ----------------
// One block per coarse bucket; 512 threads = NB1. Hillis-Steele scan in LDS.
// offs_t[k*NB1 + b] = sum_{b'<b} hist[b'][k];  bcur[k] = total.

__global__ __launch_bounds__(NB1) void bucket_prefix(const unsigned* __restrict__ hist,
                                                     unsigned* __restrict__ offs_t,
                                                     unsigned* __restrict__ bcur) {
    __shared__ unsigned sa[NB1], sb[NB1];
    int k = blockIdx.x;
    int t = threadIdx.x;
    unsigned v = hist[(size_t)t * NBK_PAD + k];
    sa[t] = v;
    __syncthreads();
    unsigned* src = sa;
    unsigned* dst = sb;
    for (int d = 1; d < NB1; d <<= 1) {
        unsigned x = src[t] + (t >= d ? src[t - d] : 0u);
        dst[t] = x;
        __syncthreads();
        unsigned* tmp = src; src = dst; dst = tmp;
    }
    unsigned inc = src[t];
    offs_t[(size_t)k * NB1 + t] = inc - v;                  // exclusive
    if (t == NB1 - 1) bcur[k] = inc;
}

// ---------------- GEMM core (device fn): out[m,128] (fp16) = (relu?)in @ W (*dis?) ----------------

template <bool RELU, bool SCALE, typename InT>
__device__ __forceinline__ void gemm_core(int bid, const InT* __restrict__ in,
                                          const unsigned short* __restrict__ whi,
                                          const unsigned short* __restrict__ wlo,
                                          const float* __restrict__ dis,
                                          _Float16* __restrict__ out) {
    int lane = threadIdx.x & 63;
    int wid = threadIdx.x >> 6;
    int cg = wid & 1;
    int rg = wid >> 1;
    int l16 = lane & 15;
    int quad = lane >> 4;
    int koff_base = quad * 8;

    short8 bhi[4][4], blo[4][4];
#pragma unroll
    for (int t = 0; t < 4; t++) {
        int n = cg * 64 + t * 16 + l16;
#pragma unroll
        for (int ks = 0; ks < 4; ks++) {
            int koff = ks * 32 + koff_base;
            bhi[t][ks] = *(const short8*)(whi + n * DD + koff);
            blo[t][ks] = *(const short8*)(wlo + n * DD + koff);
        }
    }

#pragma unroll
    for (int chunk = 0; chunk < 4; chunk++) {
        int base = bid * 128 + chunk * 32 + rg * 16;
        int m = base + l16;
        int mld = (m < NN) ? m : 0;
        const InT* xr = in + (size_t)mld * DD;

        short8 ahi[4], alo[4];
#pragma unroll
        for (int ks = 0; ks < 4; ks++) {
            int koff = ks * 32 + koff_base;
            float v[8];
            if constexpr (sizeof(InT) == 4) {
                float4 a0 = *(const float4*)(xr + koff);
                float4 a1 = *(const float4*)(xr + koff + 4);
                v[0] = a0.x; v[1] = a0.y; v[2] = a0.z; v[3] = a0.w;
                v[4] = a1.x; v[5] = a1.y; v[6] = a1.z; v[7] = a1.w;
            } else {
                half8 a = *(const half8*)(xr + koff);
#pragma unroll
                for (int j = 0; j < 8; j++) v[j] = (float)a[j];
            }
#pragma unroll
            for (int j = 0; j < 8; j++) {
                float xv = RELU ? fmaxf(v[j], 0.0f) : v[j];
                short h, l;
                split_trunc(xv, h, l);
                ahi[ks][j] = h;
                alo[ks][j] = l;
            }
        }

        floatx4 acc[4];
#pragma unroll
        for (int t = 0; t < 4; t++) acc[t] = (floatx4)(0.0f);

#pragma unroll
        for (int ks = 0; ks < 4; ks++) {
#pragma unroll
            for (int t = 0; t < 4; t++) {
                acc[t] = __builtin_amdgcn_mfma_f32_16x16x32_bf16(ahi[ks], bhi[t][ks], acc[t], 0, 0, 0);
                acc[t] = __builtin_amdgcn_mfma_f32_16x16x32_bf16(alo[ks], bhi[t][ks], acc[t], 0, 0, 0);
                acc[t] = __builtin_amdgcn_mfma_f32_16x16x32_bf16(ahi[ks], blo[t][ks], acc[t], 0, 0, 0);
            }
        }

#pragma unroll
        for (int r = 0; r < 4; r++) {
            int rowm = base + quad * 4 + r;
            if (rowm < NN) {
                float dsc = SCALE ? dis[rowm] : 1.0f;
                _Float16* o = out + (size_t)rowm * DD + cg * 64 + l16;
#pragma unroll
                for (int t = 0; t < 4; t++) o[t * 16] = (_Float16)(acc[t][r] * dsc);
            }
        }
    }
}

// ---------------- stage 3 scatter (device fn): single pass, deterministic bases ----------------
// Zero global atomics; per-edge LDS cursor + packed store into reserved run.

__device__ __forceinline__ void scatter_core(int bid, const int* __restrict__ row,
                                             const int* __restrict__ col,
                                             const float* __restrict__ ew,
                                             const unsigned* __restrict__ offs_t,
                                             uint2* __restrict__ staged) {
    __shared__ unsigned base1[NBUCK];               // absolute staged slot base for this block
    __shared__ unsigned cnt1[NBUCK];

    for (int k = threadIdx.x; k < NBUCK; k += 256) {
        base1[k] = (unsigned)k * CAP2 + offs_t[(size_t)k * NB1 + bid];
        cnt1[k] = 0u;
    }
    __syncthreads();

    int e0 = bid * EPB;
    int e1 = min(e0 + EPB, NE);
    for (int e = e0 + (int)threadIdx.x; e < e1; e += 256) {
        int c = col[e];
        int bk = c >> SHIFT2;
        unsigned r = base1[bk] + atomicAdd(&cnt1[bk], 1u);
        unsigned lim = (unsigned)bk * CAP2 + (CAP2 - 1);
        if (r > lim) r = lim;                       // memory safety on (impossible) overflow
        uint2 p;
        p.x = (unsigned)row[e] | ((unsigned)(c & (BWID - 1)) << 16);
        p.y = __float_as_uint(ew[e]);
        staged[r] = p;
    }
}

// ---------------- FUSED: stage-3 scatter + gemm1 (h1 = x@W1, unscaled) ----------------

__global__ __launch_bounds__(256) void gemm1_scatter(const float* __restrict__ x,
                                                     const unsigned short* __restrict__ w1hi,
                                                     const unsigned short* __restrict__ w1lo,
                                                     _Float16* __restrict__ g,
                                                     const int* __restrict__ row,
                                                     const int* __restrict__ col,
                                                     const float* __restrict__ ew,
                                                     const unsigned* __restrict__ offs_t,
                                                     uint2* __restrict__ staged) {
    if (blockIdx.x < NB1) {
        scatter_core(blockIdx.x, row, col, ew, offs_t, staged);
    } else {
        gemm_core<false, false, float>(blockIdx.x - NB1, x, w1hi, w1lo, nullptr, g);
    }
}

// layer-2 GEMM wrapper (dis folded in epilogue)
__global__ __launch_bounds__(256, 2) void gemm2(const _Float16* __restrict__ in,
                                                const unsigned short* __restrict__ whi,
                                                const unsigned short* __restrict__ wlo,
                                                const float* __restrict__ dis,
                                                _Float16* __restrict__ out) {
    gemm_core<true, true, _Float16>(blockIdx.x, in, whi, wlo, dis, out);
}

// ---------------- level-2: per-bucket node placement + dis/endarr + g *= dis ----------------
// One block per coarse bucket (128 nodes, ~2048 edges). All per-edge atomics in LDS.
// epk writes land in the block's private 64KB window -> fully packed cachelines.

__global__ __launch_bounds__(256) void bucket_place(const unsigned* __restrict__ bcur,
                                                    const uint2* __restrict__ staged,
                                                    uint2* __restrict__ epk,
                                                    float* __restrict__ dis,
                                                    int* __restrict__ endarr,
                                                    _Float16* __restrict__ g) {
    __shared__ unsigned cntN[BWID];
    __shared__ unsigned wfix[BWID];
    __shared__ float disS[BWID];

    int b = blockIdx.x;
    int node0 = b << SHIFT2;
    int nn = min(BWID, NN - node0);

    if (threadIdx.x < BWID) { cntN[threadIdx.x] = 0u; wfix[threadIdx.x] = 0u; }
    __syncthreads();

    int m = min((int)bcur[b], CAP2);
    const uint2* st = staged + (size_t)b * CAP2;

    // phase A: per-node count + fixed-point weight sum (LDS atomics)
    for (int j = threadIdx.x; j < m; j += 256) {
        uint2 p = st[j];
        int ln = (p.x >> 16) & (BWID - 1);
        atomicAdd(&cntN[ln], 1u);
        float w = __uint_as_float(p.y);
        atomicAdd(&wfix[ln], (unsigned)(w * FIX_SCALE + 0.5f));
    }
    __syncthreads();

    // phase B: dis, endarr; reset cursors
    if (threadIdx.x < (unsigned)nn) {
        int i = node0 + threadIdx.x;
        float deg = 1.0f + (float)wfix[threadIdx.x] * (1.0f / FIX_SCALE);  // +1 self-loop
        float d = rsqrtf(deg);
        disS[threadIdx.x] = d;
        dis[i] = d;
        endarr[i] = (i << 6) + min((int)cntN[threadIdx.x], CAP);
        cntN[threadIdx.x] = 0u;                    // reuse as rank cursor
    }
    __syncthreads();

    // phase C: rank via LDS cursor, write epk into private window
    for (int j = threadIdx.x; j < m; j += 256) {
        uint2 p = st[j];
        int ln = (p.x >> 16) & (BWID - 1);
        unsigned r = atomicAdd(&cntN[ln], 1u);
        if (r < CAP) {
            int c = node0 + ln;
            uint2 q;
            q.x = (p.x & 0xFFFFu) << 7;            // row * DD (pre-scaled gather index)
            q.y = p.y;
            epk[(c << 6) + (int)r] = q;
        }
    }

    // phase D: g[node0..node0+nn) *= dis (coalesced half8)
    half8* gb = (half8*)(g + (size_t)node0 * DD);
    for (int idx = threadIdx.x; idx < nn * 16; idx += 256) {
        float d = disS[idx >> 4];
        half8 hv = gb[idx];
#pragma unroll
        for (int jj = 0; jj < 8; jj++) hv[jj] = (_Float16)((float)hv[jj] * d);
        gb[idx] = hv;
    }
}

// ---------------- bucket gather aggregation (fp16 g, f32 accumulate) ----------------
// One wave per node; half-waves on alternating slots, 4x unrolled -> 8 gathers in flight.
// out[i] = b + dis_i * (sum_e ew_e * g[row_e] + g[i]),  g = dis*h

template <typename OutT>
__global__ __launch_bounds__(256) void agg_half(const int* __restrict__ endarr,
                                                const uint2* __restrict__ epk,
                                                const _Float16* __restrict__ g,
                                                const float* __restrict__ dis,
                                                const float* __restrict__ bias,
                                                OutT* __restrict__ out) {
    int i = (blockIdx.x * blockDim.x + threadIdx.x) >> 6;   // node
    int lane = threadIdx.x & 63;
    int s = lane & 31;
    int half = lane >> 5;
    if (i >= NN) return;

    half4 gv = *(const half4*)(g + (size_t)i * DD + s * 4);  // self-loop term g_i
    float4 bb = ((const float4*)bias)[s];
    float d = dis[i];

    float ax = 0.0f, ay = 0.0f, az = 0.0f, aw = 0.0f;

    int start = i << 6;
    int end = endarr[i];
    int j = start + half;
    for (; j + 6 < end; j += 8) {
        uint2 p0 = epk[j], p1 = epk[j + 2], p2 = epk[j + 4], p3 = epk[j + 6];
        half4 v0 = *(const half4*)(g + p0.x + s * 4);
        half4 v1 = *(const half4*)(g + p1.x + s * 4);
        half4 v2 = *(const half4*)(g + p2.x + s * 4);
        half4 v3 = *(const half4*)(g + p3.x + s * 4);
        float n0 = __uint_as_float(p0.y), n1 = __uint_as_float(p1.y);
        float n2 = __uint_as_float(p2.y), n3 = __uint_as_float(p3.y);
        ax = fmaf(n0, (float)v0.x, ax); ay = fmaf(n0, (float)v0.y, ay);
        az = fmaf(n0, (float)v0.z, az); aw = fmaf(n0, (float)v0.w, aw);
        ax = fmaf(n1, (float)v1.x, ax); ay = fmaf(n1, (float)v1.y, ay);
        az = fmaf(n1, (float)v1.z, az); aw = fmaf(n1, (float)v1.w, aw);
        ax = fmaf(n2, (float)v2.x, ax); ay = fmaf(n2, (float)v2.y, ay);
        az = fmaf(n2, (float)v2.z, az); aw = fmaf(n2, (float)v2.w, aw);
        ax = fmaf(n3, (float)v3.x, ax); ay = fmaf(n3, (float)v3.y, ay);
        az = fmaf(n3, (float)v3.z, az); aw = fmaf(n3, (float)v3.w, aw);
    }
    for (; j < end; j += 2) {
        uint2 p = epk[j];
        float nm = __uint_as_float(p.y);
        half4 v = *(const half4*)(g + p.x + s * 4);
        ax = fmaf(nm, (float)v.x, ax); ay = fmaf(nm, (float)v.y, ay);
        az = fmaf(nm, (float)v.z, az); aw = fmaf(nm, (float)v.w, aw);
    }

    ax += __shfl_xor(ax, 32);
    ay += __shfl_xor(ay, 32);
    az += __shfl_xor(az, 32);
    aw += __shfl_xor(aw, 32);

    if (half == 0) {
        float ox = bb.x + d * (ax + (float)gv.x);
        float oy = bb.y + d * (ay + (float)gv.y);
        float oz = bb.z + d * (az + (float)gv.z);
        float ow = bb.w + d * (aw + (float)gv.w);
        if constexpr (sizeof(OutT) == 2) {
            half4 o;
            o.x = (_Float16)ox; o.y = (_Float16)oy;
            o.z = (_Float16)oz; o.w = (_Float16)ow;
            *(half4*)(out + (size_t)i * DD + s * 4) = o;
        } else {
            float4 o;
            o.x = ox; o.y = oy; o.z = oz; o.w = ow;
            ((float4*)(out + (size_t)i * DD))[s] = o;
        }
    }
}

// ---------------- launch ----------------

extern "C" void kernel_launch(void* const* d_in, const int* in_sizes, int n_in,
                              void* d_out, int out_size, void* d_ws, size_t ws_size,
                              hipStream_t stream) {
    const float* x  = (const float*)d_in[0];
    const int*   ei = (const int*)d_in[1];
    const float* ew = (const float*)d_in[2];
    const float* W1 = (const float*)d_in[3];
    const float* b1 = (const float*)d_in[4];
    const float* W2 = (const float*)d_in[5];
    const float* b2 = (const float*)d_in[6];
    float* out = (float*)d_out;

    // workspace layout (4B words) — same 54.9MB footprint as before
    float* ws      = (float*)d_ws;
    float* dis     = ws;                                        // [0, 50000)
    int*   endarr  = (int*)(ws + 50000);                        // [50000, 100000)
    unsigned* bcur = (unsigned*)(ws + 100000);                  // NBUCK u32
    unsigned* hist = (unsigned*)(ws + 150000);                  // NB1*NBK_PAD = 200704 words
    unsigned* offs_t = (unsigned*)(ws + 400000);                // NBUCK*NB1 = 200192 words
    uint2* epk     = (uint2*)(ws + 900000);                     // NN*CAP uint2 = 6.4M words
    _Float16* gbuf = (_Float16*)(ws + 7300000);                 // NN*DD fp16 = 3.2M words
    unsigned short* wt1hi = (unsigned short*)(ws + 10500000);   // 8192 words each
    unsigned short* wt1lo = (unsigned short*)(ws + 10508192);
    unsigned short* wt2hi = (unsigned short*)(ws + 10516384);
    unsigned short* wt2lo = (unsigned short*)(ws + 10524576);
    _Float16* out1 = (_Float16*)(ws + 10532768);                // NN*DD fp16 = 3.2M words
    // staged aliases the out1 region: staged is dead before agg1 writes out1.
    // NBUCK*CAP2 uint2 = 2,001,920 words <= 3,200,000 words available.
    uint2* staged  = (uint2*)(ws + 10532768);

    const int* rowi = ei;
    const int* coli = ei + NE;

    // ---- 1: per-block histogram + split W1/W2 ----
    init_hist<<<NB1 + (2 * NWELEM) / 256, 256, 0, stream>>>(
        coli, hist, W1, W2, wt1hi, wt1lo, wt2hi, wt2lo);

    // ---- 2: per-bucket prefix over blocks -> deterministic run bases ----
    bucket_prefix<<<NBUCK, NB1, 0, stream>>>(hist, offs_t, bcur);

    // ---- 3: FUSED single-pass edge scatter + gemm1 (h1 = x@W1, unscaled) ----
    gemm1_scatter<<<NB1 + GEMM_GRID, 256, 0, stream>>>(
        x, wt1hi, wt1lo, gbuf, rowi, coli, ew, offs_t, staged);

    // ---- 4: level-2 bucket placement + dis/endarr + g1 *= dis ----
    bucket_place<<<NBUCK, 256, 0, stream>>>(bcur, staged, epk, dis, endarr, gbuf);

    const int agg_grid = (NN * 64) / 256 + 1;

    // ---- 5: out1 = b1 + dis*(edge_sum + g1)  (fp16) ----
    agg_half<_Float16><<<agg_grid, 256, 0, stream>>>(endarr, epk, gbuf, dis, b1, out1);

    // ---- 6: g2 = (relu(out1)@W2)*dis  (fp16) ----
    gemm2<<<GEMM_GRID, 256, 0, stream>>>(out1, wt2hi, wt2lo, dis, gbuf);

    // ---- 7: out = b2 + dis*(edge_sum + g2)  (f32) ----
    agg_half<float><<<agg_grid, 256, 0, stream>>>(endarr, epk, gbuf, dis, b2, out);
}

// Round 3
// 223.902 us; speedup vs baseline: 1.0149x; 1.0149x over previous
//
#include <hip/hip_runtime.h>

#define NN 50000
#define NE 800000
#define DD 128

#define CAP 64                                     // slots per node bucket (P(deg>=64) ~ 1e-55)
#define FIX_SCALE 16777216.0f                      // 2^24
#define LOW40 ((1ULL << 40) - 1)
#define NWELEM 16384                               // per weight matrix
#define GEMM_GRID ((NN + 127) / 128)               // 391

// two-level bucket sort params
#define SHIFT2 7
#define BWID 128                                   // nodes per coarse bucket (1<<SHIFT2)
#define NBUCK ((NN + BWID - 1) / BWID)             // 391 coarse buckets
#define CAP2 2560                                  // slots per coarse bucket (mean 2048, +11 sigma)
#define NB1 500                                    // scatter/histogram blocks (NE/NB1 = 1600 exact)
#define NB1PAD 512
#define EPB (NE / NB1)                             // 1600 edges per block, 16B-aligned
#define EQ4 (EPB / 4)                              // 400 quads per block
#define NBK_PAD 392                                // hist row stride

typedef __attribute__((ext_vector_type(8))) short short8;
typedef __attribute__((ext_vector_type(4))) float floatx4;
typedef __attribute__((ext_vector_type(4))) _Float16 half4;
typedef __attribute__((ext_vector_type(8))) _Float16 half8;

// ---------------- bf16 split (truncation; err ~2^-16 rel) ----------------

__device__ __forceinline__ void split_trunc(float x, short& hi, short& lo) {
    unsigned uh = __float_as_uint(x) >> 16;
    hi = (short)uh;
    float r = x - __uint_as_float(uh << 16);
    lo = (short)(__float_as_uint(r) >> 16);
}

// ---------------- stage 1: per-block edge histogram (fused with W split) ----------------

__global__ __launch_bounds__(256) void init_hist(const int* __restrict__ col,
                                                 unsigned* __restrict__ hist,
                                                 const float* __restrict__ W1, const float* __restrict__ W2,
                                                 unsigned short* __restrict__ w1hi, unsigned short* __restrict__ w1lo,
                                                 unsigned short* __restrict__ w2hi, unsigned short* __restrict__ w2lo) {
    if (blockIdx.x < NB1) {
        __shared__ unsigned h[NBUCK];
        for (int k = threadIdx.x; k < NBUCK; k += 256) h[k] = 0u;
        __syncthreads();
        const int4* c4p = (const int4*)(col + blockIdx.x * EPB);
#pragma unroll
        for (int it = 0; it < 2; it++) {
            int q = it * 256 + (int)threadIdx.x;
            if (q < EQ4) {
                int4 c4 = c4p[q];
                atomicAdd(&h[c4.x >> SHIFT2], 1u);
                atomicAdd(&h[c4.y >> SHIFT2], 1u);
                atomicAdd(&h[c4.z >> SHIFT2], 1u);
                atomicAdd(&h[c4.w >> SHIFT2], 1u);
            }
        }
        __syncthreads();
        unsigned* hb = hist + (size_t)blockIdx.x * NBK_PAD;
        for (int k = threadIdx.x; k < NBUCK; k += 256) hb[k] = h[k];
    } else {
        int u = (blockIdx.x - NB1) * 256 + threadIdx.x;     // [0, 2*NWELEM)
        int which = u >> 14;
        int idx = u & (NWELEM - 1);
        int k = idx >> 7, n = idx & 127;
        const float* W = which ? W2 : W1;
        unsigned short* whi = which ? w2hi : w1hi;
        unsigned short* wlo = which ? w2lo : w1lo;
        short h, l;
        split_trunc(W[idx], h, l);
        whi[n * DD + k] = (unsigned short)h;
        wlo[n * DD + k] = (unsigned short)l;
    }
}

// ---------------- stage 2: per-bucket exclusive prefix over blocks ----------------
// One block per coarse bucket; 512 threads >= NB1. Hillis-Steele scan in LDS.
// offs_t[k*NB1PAD + b] = sum_{b'<b} hist[b'][k];  bcur[k] = total.

__global__ __launch_bounds__(512) void bucket_prefix(const unsigned* __restrict__ hist,
                                                     unsigned* __restrict__ offs_t,
                                                     unsigned* __restrict__ bcur) {
    __shared__ unsigned sa[512], sb[512];
    int k = blockIdx.x;
    int t = threadIdx.x;
    unsigned v = (t < NB1) ? hist[(size_t)t * NBK_PAD + k] : 0u;
    sa[t] = v;
    __syncthreads();
    unsigned* src = sa;
    unsigned* dst = sb;
    for (int d = 1; d < 512; d <<= 1) {
        unsigned x = src[t] + (t >= d ? src[t - d] : 0u);
        dst[t] = x;
        __syncthreads();
        unsigned* tmp = src; src = dst; dst = tmp;
    }
    unsigned inc = src[t];
    if (t < NB1) offs_t[(size_t)k * NB1PAD + t] = inc - v;  // exclusive
    if (t == 511) bcur[k] = inc;
}

// ---------------- GEMM core (device fn): out[m,128] (fp16) = (relu?)in @ W ----------------

template <bool RELU, typename InT>
__device__ __forceinline__ void gemm_core(int bid, const InT* __restrict__ in,
                                          const unsigned short* __restrict__ whi,
                                          const unsigned short* __restrict__ wlo,
                                          _Float16* __restrict__ out) {
    int lane = threadIdx.x & 63;
    int wid = threadIdx.x >> 6;
    int cg = wid & 1;
    int rg = wid >> 1;
    int l16 = lane & 15;
    int quad = lane >> 4;
    int koff_base = quad * 8;

    short8 bhi[4][4], blo[4][4];
#pragma unroll
    for (int t = 0; t < 4; t++) {
        int n = cg * 64 + t * 16 + l16;
#pragma unroll
        for (int ks = 0; ks < 4; ks++) {
            int koff = ks * 32 + koff_base;
            bhi[t][ks] = *(const short8*)(whi + n * DD + koff);
            blo[t][ks] = *(const short8*)(wlo + n * DD + koff);
        }
    }

#pragma unroll
    for (int chunk = 0; chunk < 4; chunk++) {
        int base = bid * 128 + chunk * 32 + rg * 16;
        int m = base + l16;
        int mld = (m < NN) ? m : 0;
        const InT* xr = in + (size_t)mld * DD;

        short8 ahi[4], alo[4];
#pragma unroll
        for (int ks = 0; ks < 4; ks++) {
            int koff = ks * 32 + koff_base;
            float v[8];
            if constexpr (sizeof(InT) == 4) {
                float4 a0 = *(const float4*)(xr + koff);
                float4 a1 = *(const float4*)(xr + koff + 4);
                v[0] = a0.x; v[1] = a0.y; v[2] = a0.z; v[3] = a0.w;
                v[4] = a1.x; v[5] = a1.y; v[6] = a1.z; v[7] = a1.w;
            } else {
                half8 a = *(const half8*)(xr + koff);
#pragma unroll
                for (int j = 0; j < 8; j++) v[j] = (float)a[j];
            }
#pragma unroll
            for (int j = 0; j < 8; j++) {
                float xv = RELU ? fmaxf(v[j], 0.0f) : v[j];
                short h, l;
                split_trunc(xv, h, l);
                ahi[ks][j] = h;
                alo[ks][j] = l;
            }
        }

        floatx4 acc[4];
#pragma unroll
        for (int t = 0; t < 4; t++) acc[t] = (floatx4)(0.0f);

#pragma unroll
        for (int ks = 0; ks < 4; ks++) {
#pragma unroll
            for (int t = 0; t < 4; t++) {
                acc[t] = __builtin_amdgcn_mfma_f32_16x16x32_bf16(ahi[ks], bhi[t][ks], acc[t], 0, 0, 0);
                acc[t] = __builtin_amdgcn_mfma_f32_16x16x32_bf16(alo[ks], bhi[t][ks], acc[t], 0, 0, 0);
                acc[t] = __builtin_amdgcn_mfma_f32_16x16x32_bf16(ahi[ks], blo[t][ks], acc[t], 0, 0, 0);
            }
        }

#pragma unroll
        for (int r = 0; r < 4; r++) {
            int rowm = base + quad * 4 + r;
            if (rowm < NN) {
                _Float16* o = out + (size_t)rowm * DD + cg * 64 + l16;
#pragma unroll
                for (int t = 0; t < 4; t++) o[t * 16] = (_Float16)acc[t][r];
            }
        }
    }
}

// ---------------- stage 3 scatter (device fn): single pass, deterministic bases ----------------
// Zero global atomics; vectorized quad loads -> 4 independent {LDS cursor + store} per step.

__device__ __forceinline__ void scatter_core(int bid, const int* __restrict__ row,
                                             const int* __restrict__ col,
                                             const float* __restrict__ ew,
                                             const unsigned* __restrict__ offs_t,
                                             uint2* __restrict__ staged) {
    __shared__ unsigned base1[NBUCK];               // absolute staged slot base for this block
    __shared__ unsigned cnt1[NBUCK];

    for (int k = threadIdx.x; k < NBUCK; k += 256) {
        base1[k] = (unsigned)k * CAP2 + offs_t[(size_t)k * NB1PAD + bid];
        cnt1[k] = 0u;
    }
    __syncthreads();

    int e0 = bid * EPB;
    const int4* c4p = (const int4*)(col + e0);
    const int4* r4p = (const int4*)(row + e0);
    const float4* w4p = (const float4*)(ew + e0);

#pragma unroll
    for (int it = 0; it < 2; it++) {
        int q = it * 256 + (int)threadIdx.x;
        if (q < EQ4) {
            int4 c4 = c4p[q];
            int4 r4 = r4p[q];
            float4 w4 = w4p[q];
            int cc[4] = {c4.x, c4.y, c4.z, c4.w};
            int rr[4] = {r4.x, r4.y, r4.z, r4.w};
            float wv[4] = {w4.x, w4.y, w4.z, w4.w};
#pragma unroll
            for (int j = 0; j < 4; j++) {
                int bk = cc[j] >> SHIFT2;
                unsigned r = base1[bk] + atomicAdd(&cnt1[bk], 1u);
                unsigned lim = (unsigned)bk * CAP2 + (CAP2 - 1);
                if (r > lim) r = lim;               // memory safety on (impossible) overflow
                uint2 p;
                p.x = (unsigned)rr[j] | ((unsigned)(cc[j] & (BWID - 1)) << 16);
                p.y = __float_as_uint(wv[j]);
                staged[r] = p;
            }
        }
    }
}

// ---------------- FUSED: stage-3 scatter + gemm1 (h1 = x@W1, raw) ----------------

__global__ __launch_bounds__(256) void gemm1_scatter(const float* __restrict__ x,
                                                     const unsigned short* __restrict__ w1hi,
                                                     const unsigned short* __restrict__ w1lo,
                                                     _Float16* __restrict__ g,
                                                     const int* __restrict__ row,
                                                     const int* __restrict__ col,
                                                     const float* __restrict__ ew,
                                                     const unsigned* __restrict__ offs_t,
                                                     uint2* __restrict__ staged) {
    if (blockIdx.x < NB1) {
        scatter_core(blockIdx.x, row, col, ew, offs_t, staged);
    } else {
        gemm_core<false, float>(blockIdx.x - NB1, x, w1hi, w1lo, g);
    }
}

// layer-2 GEMM wrapper (raw h2; dis handled in agg)
__global__ __launch_bounds__(256, 2) void gemm2(const _Float16* __restrict__ in,
                                                const unsigned short* __restrict__ whi,
                                                const unsigned short* __restrict__ wlo,
                                                _Float16* __restrict__ out) {
    gemm_core<true, _Float16>(blockIdx.x, in, whi, wlo, out);
}

// ---------------- level-2: per-bucket node placement + dis/endarr ----------------
// One block per coarse bucket (128 nodes, ~2048 edges). Edges staged ONCE into LDS;
// single packed 64-bit LDS atomic per edge for {count, weight-sum}.
// epk writes land in the block's private 64KB window -> fully packed cachelines.

__global__ __launch_bounds__(256) void bucket_place(const unsigned* __restrict__ bcur,
                                                    const uint2* __restrict__ staged,
                                                    uint2* __restrict__ epk,
                                                    float* __restrict__ dis,
                                                    int* __restrict__ endarr) {
    __shared__ uint2 sST[CAP2];                    // 20 KB edge stage
    __shared__ unsigned long long wcnt[BWID];      // (count<<40) | qsum
    __shared__ unsigned curN[BWID];

    int b = blockIdx.x;
    int node0 = b << SHIFT2;
    int nn = min(BWID, NN - node0);

    if (threadIdx.x < BWID) { wcnt[threadIdx.x] = 0ULL; curN[threadIdx.x] = 0u; }
    __syncthreads();

    int m = min((int)bcur[b], CAP2);
    const uint2* st = staged + (size_t)b * CAP2;

    // phase A: copy to LDS + packed count/weight accumulation
    for (int j = threadIdx.x; j < m; j += 256) {
        uint2 p = st[j];
        sST[j] = p;
        int ln = (p.x >> 16) & (BWID - 1);
        float w = __uint_as_float(p.y);
        unsigned q = (unsigned)(w * FIX_SCALE + 0.5f);
        atomicAdd(&wcnt[ln], (1ULL << 40) | (unsigned long long)q);
    }
    __syncthreads();

    // phase B: dis, endarr
    if (threadIdx.x < (unsigned)nn) {
        int i = node0 + threadIdx.x;
        unsigned long long cv = wcnt[threadIdx.x];
        float deg = 1.0f + (float)(cv & LOW40) * (1.0f / FIX_SCALE);   // +1 self-loop
        dis[i] = rsqrtf(deg);
        endarr[i] = (i << 6) + min((int)(cv >> 40), CAP);
    }
    __syncthreads();

    // phase C: rank via LDS cursor, write epk into private window
    for (int j = threadIdx.x; j < m; j += 256) {
        uint2 p = sST[j];
        int ln = (p.x >> 16) & (BWID - 1);
        unsigned r = atomicAdd(&curN[ln], 1u);
        if (r < CAP) {
            int c = node0 + ln;
            uint2 q;
            q.x = (p.x & 0xFFFFu) << 7;            // row * DD (pre-scaled gather index)
            q.y = p.y;                             // raw ew (dis[row] applied in agg)
            epk[(c << 6) + (int)r] = q;
        }
    }
}

// ---------------- bucket gather aggregation (fp16 h, f32 accumulate) ----------------
// Two nodes per wave (32 lanes each = one full 256B row per gather). No cross-lane reduce.
// out[i] = b + dis_i * (sum_e ew_e*dis[row_e]*h[row_e] + dis_i*h[i])

template <typename OutT>
__global__ __launch_bounds__(256) void agg_half(const int* __restrict__ endarr,
                                                const uint2* __restrict__ epk,
                                                const _Float16* __restrict__ g,
                                                const float* __restrict__ dis,
                                                const float* __restrict__ bias,
                                                OutT* __restrict__ out) {
    int w = (blockIdx.x * blockDim.x + threadIdx.x) >> 6;
    int lane = threadIdx.x & 63;
    int gi = lane >> 5;
    int s = lane & 31;
    int i = 2 * w + gi;                             // NN even; grid sized exactly

    half4 hv = *(const half4*)(g + (size_t)i * DD + s * 4);   // self-loop term h_i
    float4 bb = ((const float4*)bias)[s];
    float d = dis[i];

    float ax = 0.0f, ay = 0.0f, az = 0.0f, aw = 0.0f;

    int j = i << 6;
    int end = endarr[i];
    for (; j + 3 < end; j += 4) {
        uint4 pa = *(const uint4*)(epk + j);        // 32B-aligned: j % 4 == 0
        uint4 pb = *(const uint4*)(epk + j + 2);
        float n0 = __uint_as_float(pa.y) * dis[pa.x >> 7];
        float n1 = __uint_as_float(pa.w) * dis[pa.z >> 7];
        float n2 = __uint_as_float(pb.y) * dis[pb.x >> 7];
        float n3 = __uint_as_float(pb.w) * dis[pb.z >> 7];
        half4 v0 = *(const half4*)(g + pa.x + s * 4);
        half4 v1 = *(const half4*)(g + pa.z + s * 4);
        half4 v2 = *(const half4*)(g + pb.x + s * 4);
        half4 v3 = *(const half4*)(g + pb.z + s * 4);
        ax = fmaf(n0, (float)v0.x, ax); ay = fmaf(n0, (float)v0.y, ay);
        az = fmaf(n0, (float)v0.z, az); aw = fmaf(n0, (float)v0.w, aw);
        ax = fmaf(n1, (float)v1.x, ax); ay = fmaf(n1, (float)v1.y, ay);
        az = fmaf(n1, (float)v1.z, az); aw = fmaf(n1, (float)v1.w, aw);
        ax = fmaf(n2, (float)v2.x, ax); ay = fmaf(n2, (float)v2.y, ay);
        az = fmaf(n2, (float)v2.z, az); aw = fmaf(n2, (float)v2.w, aw);
        ax = fmaf(n3, (float)v3.x, ax); ay = fmaf(n3, (float)v3.y, ay);
        az = fmaf(n3, (float)v3.z, az); aw = fmaf(n3, (float)v3.w, aw);
    }
    for (; j < end; ++j) {
        uint2 p = epk[j];
        float nm = __uint_as_float(p.y) * dis[p.x >> 7];
        half4 v = *(const half4*)(g + p.x + s * 4);
        ax = fmaf(nm, (float)v.x, ax); ay = fmaf(nm, (float)v.y, ay);
        az = fmaf(nm, (float)v.z, az); aw = fmaf(nm, (float)v.w, aw);
    }

    float ox = bb.x + d * (ax + d * (float)hv.x);
    float oy = bb.y + d * (ay + d * (float)hv.y);
    float oz = bb.z + d * (az + d * (float)hv.z);
    float ow = bb.w + d * (aw + d * (float)hv.w);
    if constexpr (sizeof(OutT) == 2) {
        half4 o;
        o.x = (_Float16)ox; o.y = (_Float16)oy;
        o.z = (_Float16)oz; o.w = (_Float16)ow;
        *(half4*)(out + (size_t)i * DD + s * 4) = o;
    } else {
        float4 o;
        o.x = ox; o.y = oy; o.z = oz; o.w = ow;
        ((float4*)(out + (size_t)i * DD))[s] = o;
    }
}

// ---------------- launch ----------------

extern "C" void kernel_launch(void* const* d_in, const int* in_sizes, int n_in,
                              void* d_out, int out_size, void* d_ws, size_t ws_size,
                              hipStream_t stream) {
    const float* x  = (const float*)d_in[0];
    const int*   ei = (const int*)d_in[1];
    const float* ew = (const float*)d_in[2];
    const float* W1 = (const float*)d_in[3];
    const float* b1 = (const float*)d_in[4];
    const float* W2 = (const float*)d_in[5];
    const float* b2 = (const float*)d_in[6];
    float* out = (float*)d_out;

    // workspace layout (4B words)
    float* ws      = (float*)d_ws;
    float* dis     = ws;                                        // [0, 50000)
    int*   endarr  = (int*)(ws + 50000);                        // [50000, 100000)
    unsigned* bcur = (unsigned*)(ws + 100000);                  // NBUCK u32
    unsigned* hist = (unsigned*)(ws + 150000);                  // NB1*NBK_PAD = 196000 words
    unsigned* offs_t = (unsigned*)(ws + 400000);                // NBUCK*NB1PAD = 200192 words
    uint2* epk     = (uint2*)(ws + 900000);                     // NN*CAP uint2 = 6.4M words
    _Float16* gbuf = (_Float16*)(ws + 7300000);                 // NN*DD fp16 = 3.2M words
    unsigned short* wt1hi = (unsigned short*)(ws + 10500000);   // 8192 words each
    unsigned short* wt1lo = (unsigned short*)(ws + 10508192);
    unsigned short* wt2hi = (unsigned short*)(ws + 10516384);
    unsigned short* wt2lo = (unsigned short*)(ws + 10524576);
    _Float16* out1 = (_Float16*)(ws + 10532768);                // NN*DD fp16 = 3.2M words
    // staged aliases the out1 region: staged is dead before agg1 writes out1.
    // NBUCK*CAP2 uint2 = 2,001,920 words <= 3,200,000 words available.
    uint2* staged  = (uint2*)(ws + 10532768);

    const int* rowi = ei;
    const int* coli = ei + NE;

    // ---- 1: per-block histogram + split W1/W2 ----
    init_hist<<<NB1 + (2 * NWELEM) / 256, 256, 0, stream>>>(
        coli, hist, W1, W2, wt1hi, wt1lo, wt2hi, wt2lo);

    // ---- 2: per-bucket prefix over blocks -> deterministic run bases ----
    bucket_prefix<<<NBUCK, 512, 0, stream>>>(hist, offs_t, bcur);

    // ---- 3: FUSED single-pass edge scatter + gemm1 (h1 = x@W1, raw) ----
    gemm1_scatter<<<NB1 + GEMM_GRID, 256, 0, stream>>>(
        x, wt1hi, wt1lo, gbuf, rowi, coli, ew, offs_t, staged);

    // ---- 4: level-2 bucket placement + dis/endarr ----
    bucket_place<<<NBUCK, 256, 0, stream>>>(bcur, staged, epk, dis, endarr);

    const int agg_grid = (NN / 2) * 64 / 256;                   // 6250, exact

    // ---- 5: out1 = b1 + dis*(edge_sum + dis*h1)  (fp16) ----
    agg_half<_Float16><<<agg_grid, 256, 0, stream>>>(endarr, epk, gbuf, dis, b1, out1);

    // ---- 6: h2 = relu(out1)@W2  (fp16, raw) ----
    gemm2<<<GEMM_GRID, 256, 0, stream>>>(out1, wt2hi, wt2lo, gbuf);

    // ---- 7: out = b2 + dis*(edge_sum + dis*h2)  (f32) ----
    agg_half<float><<<agg_grid, 256, 0, stream>>>(endarr, epk, gbuf, dis, b2, out);
}